// Round 10
// baseline (85.858 us; speedup 1.0000x reference)
//
#include <hip/hip_runtime.h>

#define N_FFT    1024
#define HOP      256
#define BATCH    16
#define T_LEN    262144
#define PAD      512
#define N_FRAMES 1025
#define N_FREQ   513
#define FPB      16
#define NTILES   65

// skew for wave-private scratch & twiddle table (all accesses <=2-way, verified)
#define SKX(i) ((i) + ((i) >> 5))

__device__ constexpr int   R4_[16] = {0,8,4,12,2,10,6,14,1,9,5,13,3,11,7,15};
__device__ constexpr float CA_[16] = {
     1.0f,           0.92387953251f,  0.70710678119f,  0.38268343236f,
     0.0f,          -0.38268343236f, -0.70710678119f, -0.92387953251f,
    -1.0f,          -0.92387953251f, -0.70710678119f, -0.38268343236f,
     0.0f,           0.38268343236f,  0.70710678119f,  0.92387953251f};
__device__ constexpr float SA_[16] = {
     0.0f,           0.38268343236f,  0.70710678119f,  0.92387953251f,
     1.0f,           0.92387953251f,  0.70710678119f,  0.38268343236f,
     0.0f,          -0.38268343236f, -0.70710678119f, -0.92387953251f,
    -1.0f,          -0.92387953251f, -0.70710678119f, -0.38268343236f};

// Block = (batch, 16-frame tile), 256 threads = 4 waves.
// Each wave processes one frame-pair at a time, fully wave-synchronous:
// 16 complex elems/lane in registers, 2 wave-private LDS exchanges, extract
// via lane-reversal shuffle. Only the shared output tile needs barriers (5/block).
__global__ __launch_bounds__(256, 4)
void stft_kernel(const float* __restrict__ x, float* __restrict__ out,
                 unsigned long long cap)
{
    __shared__ float twr[528], twi[528];
    __shared__ float sc4[4][1056];
    __shared__ float ot[N_FREQ * 9];

    const int tid  = threadIdx.x;
    const int wv   = tid >> 6;
    const int lane = tid & 63;
    const int tile = blockIdx.x % NTILES;
    const int b    = blockIdx.x / NTILES;
    const int t0   = tile * FPB;
    const float TWO_PI = 6.283185307179586f;

    // twiddle table tw[k] = exp(-2*pi*i*k/1024), k in [0,512)
    for (int k = tid; k < 512; k += 256) {
        float ang = -TWO_PI * (float)k * (1.0f / 1024.0f);
        twr[SKX(k)] = cosf(ang);
        twi[SKX(k)] = sinf(ang);
    }
    __syncthreads();

    float* sc = sc4[wv];
    const float* xb = x + (size_t)b * T_LEN;
    const int c6 = (int)(__brev((unsigned)lane) >> 26);  // rev6(lane)
    const int lo = lane & 15;
    // window base: w(n)=0.5-0.5cos(A+B), n=64k+c6, A=pi*k/8 (const), B=pi*c6/512
    const float cB = cosf((float)c6 * (TWO_PI / 1024.0f));
    const float sB = sinf((float)c6 * (TWO_PI / 1024.0f));

    for (int chunk = 0; chunk < 2; ++chunk) {
        const int tA = t0 + chunk * 8 + 2 * wv;     // this wave's frame A
        const int baseA = tA * HOP - PAD;

        float ar[16], ai[16];
        // ---- load bit-reversed: A[lane*16+r] = w*x[rev10(pos)]; B packed in im
        #pragma unroll
        for (int r = 0; r < 16; ++r) {
            const int k = R4_[r];
            const int n = (k << 6) | c6;            // rev10(lane*16+r)
            const float w = 0.5f - 0.5f * (CA_[k] * cB - SA_[k] * sB);
            int pa = baseA + n;
            pa = (pa < 0) ? -pa : pa;
            pa = (pa >= T_LEN) ? (2 * (T_LEN - 1) - pa) : pa;
            int pb = baseA + HOP + n;
            pb = (pb < 0) ? -pb : pb;
            pb = (pb >= T_LEN) ? (2 * (T_LEN - 1) - pb) : pb;
            ar[r] = w * xb[pa];
            ai[r] = w * xb[pb];
        }

        // ---- stages 0-3: register-local, constant twiddles e^{-i*pi*j/h}
        #pragma unroll
        for (int s = 0; s < 4; ++s) {
            const int h = 1 << s;
            #pragma unroll
            for (int kk = 0; kk < 8; ++kk) {
                const int j  = kk & (h - 1);
                const int i0 = ((kk >> s) << (s + 1)) | j;
                const int i1 = i0 + h;
                const int tk = j << (3 - s);
                const float wr = CA_[tk], wi = -SA_[tk];
                const float tr = ar[i1] * wr - ai[i1] * wi;
                const float ti = ar[i1] * wi + ai[i1] * wr;
                ar[i1] = ar[i0] - tr;  ai[i1] = ai[i0] - ti;
                ar[i0] += tr;          ai[i0] += ti;
            }
        }

        // ---- exchange 1 (wave-private, no barrier): reg bits b3..b0 -> b7..b4
        #pragma unroll
        for (int r = 0; r < 16; ++r) sc[SKX((lane << 4) | r)] = ar[r];
        #pragma unroll
        for (int r = 0; r < 16; ++r)
            ar[r] = sc[SKX(((lane >> 4) << 8) | (r << 4) | lo)];
        #pragma unroll
        for (int r = 0; r < 16; ++r) sc[SKX((lane << 4) | r)] = ai[r];
        #pragma unroll
        for (int r = 0; r < 16; ++r)
            ai[r] = sc[SKX(((lane >> 4) << 8) | (r << 4) | lo)];

        // ---- stages 4-7: register-local, j = lo + 16*j'
        #pragma unroll
        for (int s4 = 0; s4 < 4; ++s4) {
            const int h = 1 << s4;
            #pragma unroll
            for (int kk = 0; kk < 8; ++kk) {
                const int j  = kk & (h - 1);
                const int i0 = ((kk >> s4) << (s4 + 1)) | j;
                const int i1 = i0 + h;
                const int idx = (lo + (j << 4)) << (5 - s4);
                const float wr = twr[SKX(idx)], wi = twi[SKX(idx)];
                const float tr = ar[i1] * wr - ai[i1] * wi;
                const float ti = ar[i1] * wi + ai[i1] * wr;
                ar[i1] = ar[i0] - tr;  ai[i1] = ai[i0] - ti;
                ar[i0] += tr;          ai[i0] += ti;
            }
        }

        // ---- exchange 2: new ownership lane = pos&63, reg = pos>>6
        #pragma unroll
        for (int r = 0; r < 16; ++r)
            sc[SKX(((lane >> 4) << 8) | (r << 4) | lo)] = ar[r];
        #pragma unroll
        for (int r = 0; r < 16; ++r) ar[r] = sc[SKX((r << 6) | lane)];
        #pragma unroll
        for (int r = 0; r < 16; ++r)
            sc[SKX(((lane >> 4) << 8) | (r << 4) | lo)] = ai[r];
        #pragma unroll
        for (int r = 0; r < 16; ++r) ai[r] = sc[SKX((r << 6) | lane)];

        // ---- stage 8: pairs (r, r+4), j = (i0&3)*64 + lane
        #pragma unroll
        for (int kk = 0; kk < 8; ++kk) {
            const int j  = kk & 3;
            const int i0 = ((kk >> 2) << 3) | j;
            const int i1 = i0 + 4;
            const int idx = (((i0 & 3) << 6) | lane) << 1;
            const float wr = twr[SKX(idx)], wi = twi[SKX(idx)];
            const float tr = ar[i1] * wr - ai[i1] * wi;
            const float ti = ar[i1] * wi + ai[i1] * wr;
            ar[i1] = ar[i0] - tr;  ai[i1] = ai[i0] - ti;
            ar[i0] += tr;          ai[i0] += ti;
        }
        // ---- stage 9: pairs (r, r+8), j = i0*64 + lane
        #pragma unroll
        for (int kk = 0; kk < 8; ++kk) {
            const int i0 = kk, i1 = kk + 8;
            const int idx = (i0 << 6) | lane;
            const float wr = twr[SKX(idx)], wi = twi[SKX(idx)];
            const float tr = ar[i1] * wr - ai[i1] * wi;
            const float ti = ar[i1] * wi + ai[i1] * wr;
            ar[i1] = ar[i0] - tr;  ai[i1] = ai[i0] - ti;
            ar[i0] += tr;          ai[i0] += ti;
        }

        // ---- extract Re of both real frames: Z[f] = ar[e],ai[e] at f=64e+lane;
        //      partner Z[1024-f] = reg 15-e at lane 64-lane (lane-reversal shfl)
        const int src = (64 - lane) & 63;
        #pragma unroll
        for (int e = 0; e < 8; ++e) {
            float srE = __shfl(ar[15 - e], src);
            float siE = __shfl(ai[15 - e], src);
            if (lane == 0) { srE = ar[(16 - e) & 15]; siE = ai[(16 - e) & 15]; }
            const int f = (e << 6) | lane;
            ot[f * 9 + 2 * wv]     = 0.5f * (ar[e] + srE);
            ot[f * 9 + 2 * wv + 1] = 0.5f * (ai[e] + siE);
        }
        if (lane == 0) {                    // f = 512 (self-paired)
            ot[512 * 9 + 2 * wv]     = ar[8];
            ot[512 * 9 + 2 * wv + 1] = ai[8];
        }

        __syncthreads();
        // ---- flush 8 columns, 32B-contiguous row segments
        const int tc0 = t0 + chunk * 8;
        for (int it = 0; it < 17; ++it) {
            const int idx = tid + it * 256;
            if (idx < N_FREQ * 8) {
                const int f = idx >> 3, c = idx & 7;
                const int t = tc0 + c;
                if (t < N_FRAMES) {
                    unsigned long long o =
                        (unsigned long long)(b * N_FREQ + f) * N_FRAMES
                        + (unsigned long long)t;
                    if (o < cap) out[o] = ot[f * 9 + c];
                }
            }
        }
        __syncthreads();
    }
}

extern "C" void kernel_launch(void* const* d_in, const int* in_sizes, int n_in,
                              void* d_out, int out_size, void* d_ws, size_t ws_size,
                              hipStream_t stream)
{
    const float* x = (const float*)d_in[0];
    float* out = (float*)d_out;
    if (!x || !out || out_size <= 0) return;

    unsigned long long cap = (unsigned long long)(long long)out_size;

    dim3 grid(BATCH * NTILES);   // 1040 blocks
    dim3 block(256);
    stft_kernel<<<grid, block, 0, stream>>>(x, out, cap);
}

// Round 11
// 39.859 us; speedup vs baseline: 2.1540x; 2.1540x over previous
//
#include <hip/hip_runtime.h>

#define N_FFT    1024
#define HOP      256
#define BATCH    16
#define T_LEN    262144
#define PAD      512
#define N_FRAMES 1025
#define N_FREQ   513
#define FPB      8
#define NTILES   129        // ceil(1025/8)

// skewed output-tile index: conflict-free for bitrev-order writes AND flush reads
#define OTI(f) ((f) * 9 + ((f) >> 4))
#define OT_SZ  (OTI(512) + 16)

__device__ constexpr int   R4_[16] = {0,8,4,12,2,10,6,14,1,9,5,13,3,11,7,15}; // rev4
__device__ constexpr float CA_[16] = {   // cos(2*pi*k/16)
     1.0f,           0.92387953251f,  0.70710678119f,  0.38268343236f,
     0.0f,          -0.38268343236f, -0.70710678119f, -0.92387953251f,
    -1.0f,          -0.92387953251f, -0.70710678119f, -0.38268343236f,
     0.0f,           0.38268343236f,  0.70710678119f,  0.92387953251f};
__device__ constexpr float SA_[16] = {   // sin(2*pi*k/16)
     0.0f,           0.38268343236f,  0.70710678119f,  0.92387953251f,
     1.0f,           0.92387953251f,  0.70710678119f,  0.38268343236f,
     0.0f,          -0.38268343236f, -0.70710678119f, -0.92387953251f,
    -1.0f,          -0.92387953251f, -0.70710678119f, -0.38268343236f};

// Block = (batch, 8-frame tile), 256 threads = 4 waves; wave wv owns frames
// (t0+2wv, t0+2wv+1) packed as z = a + i*b. Even-part s[n] = (z[n]+z[-n])/2
// makes S = FFT(s) satisfy ReS = ReA, ImS = ReB. 1024-pt DIF FFT entirely in
// registers (16 cplx/lane): stages 512..64 reg-local, 32..1 via shfl_xor;
// twiddles are kernel-invariant per-lane registers. LDS = output tile only.
__global__ __launch_bounds__(256)
void stft_kernel(const float* __restrict__ x, float* __restrict__ out,
                 unsigned long long cap)
{
    __shared__ float ot[OT_SZ];

    const int tid  = threadIdx.x;
    const int wv   = tid >> 6;
    const int lane = tid & 63;
    const int tile = blockIdx.x % NTILES;
    const int b    = blockIdx.x / NTILES;
    const int t0   = tile * FPB;
    const int tA   = t0 + 2 * wv;

    const float TWO_PI = 6.283185307179586f;

    // ---- per-lane twiddle bases: wL = exp(-2pi*i*lane/1024), powers by squaring
    float sL, cL;
    sincosf(TWO_PI * (float)lane * (1.0f / 1024.0f), &sL, &cL);
    const float w1r = cL,  w1i = -sL;
    const float w2r = w1r*w1r - w1i*w1i,     w2i = 2.0f*w1r*w1i;
    const float w4r = w2r*w2r - w2i*w2i,     w4i = 2.0f*w2r*w2i;
    const float w8r = w4r*w4r - w4i*w4i,     w8i = 2.0f*w4r*w4i;
    const float w16r = w8r*w8r - w8i*w8i,    w16i = 2.0f*w8r*w8i;
    const float w32r = w16r*w16r - w16i*w16i, w32i = 2.0f*w16r*w16i;
    const float w64r  = CA_[lane & 15],        w64i  = -SA_[lane & 15];
    const float w128r = CA_[(lane & 7) << 1],  w128i = -SA_[(lane & 7) << 1];
    const float w256r = CA_[(lane & 3) << 2],  w256i = -SA_[(lane & 3) << 2];

    // ---- load + window (coalesced: pos = r*64+lane), z = wA + i*wB ----
    const float* xb = x + (size_t)b * T_LEN;
    const int baseA = tA * HOP - PAD;
    float zr_[16], zi_[16];
    #pragma unroll
    for (int r = 0; r < 16; ++r) {
        const int n = (r << 6) | lane;
        const float w = 0.5f - 0.5f * (CA_[r] * cL - SA_[r] * sL);
        int pa = baseA + n;
        pa = (pa < 0) ? -pa : pa;
        pa = (pa >= T_LEN) ? (2 * (T_LEN - 1) - pa) : pa;
        int pb = baseA + HOP + n;
        pb = (pb < 0) ? -pb : pb;
        pb = (pb >= T_LEN) ? (2 * (T_LEN - 1) - pb) : pb;
        zr_[r] = w * xb[pa];
        zi_[r] = w * xb[pb];
    }

    // ---- even part: s[n] = (z[n] + z[(1024-n)&1023])/2 via lane-reversal shfl
    const int src = (64 - lane) & 63;
    float sr_[16], si_[16];
    #pragma unroll
    for (int r = 0; r < 16; ++r) {
        float pr = __shfl(zr_[15 - r], src);
        float pi = __shfl(zi_[15 - r], src);
        if (lane == 0) { pr = zr_[(16 - r) & 15]; pi = zi_[(16 - r) & 15]; }
        sr_[r] = 0.5f * (zr_[r] + pr);
        si_[r] = 0.5f * (zi_[r] + pi);
    }

    // ---- DIF stage h=512: pairs (r, r+8), tw = wL * C16^r ----
    #pragma unroll
    for (int r = 0; r < 8; ++r) {
        const int v = r + 8;
        float dr = sr_[r] - sr_[v], di = si_[r] - si_[v];
        sr_[r] += sr_[v];  si_[r] += si_[v];
        float er = dr * w1r - di * w1i;
        float ei = dr * w1i + di * w1r;
        sr_[v] = er * CA_[r] + ei * SA_[r];
        si_[v] = ei * CA_[r] - er * SA_[r];
    }
    // ---- stage h=256: pairs (8g+k, +4), tw = wL2 * C8^k ----
    #pragma unroll
    for (int g = 0; g < 2; ++g)
    #pragma unroll
    for (int k = 0; k < 4; ++k) {
        const int u = (g << 3) + k, v = u + 4;
        float dr = sr_[u] - sr_[v], di = si_[u] - si_[v];
        sr_[u] += sr_[v];  si_[u] += si_[v];
        float er = dr * w2r - di * w2i;
        float ei = dr * w2i + di * w2r;
        sr_[v] = er * CA_[2 * k] + ei * SA_[2 * k];
        si_[v] = ei * CA_[2 * k] - er * SA_[2 * k];
    }
    // ---- stage h=128: pairs (4g+k, +2), tw = wL4 * C4^k ----
    #pragma unroll
    for (int g = 0; g < 4; ++g)
    #pragma unroll
    for (int k = 0; k < 2; ++k) {
        const int u = (g << 2) + k, v = u + 2;
        float dr = sr_[u] - sr_[v], di = si_[u] - si_[v];
        sr_[u] += sr_[v];  si_[u] += si_[v];
        float er = dr * w4r - di * w4i;
        float ei = dr * w4i + di * w4r;
        sr_[v] = er * CA_[4 * k] + ei * SA_[4 * k];
        si_[v] = ei * CA_[4 * k] - er * SA_[4 * k];
    }
    // ---- stage h=64: pairs (u, u+1), tw = wL8 ----
    #pragma unroll
    for (int u = 0; u < 16; u += 2) {
        const int v = u + 1;
        float dr = sr_[u] - sr_[v], di = si_[u] - si_[v];
        sr_[u] += sr_[v];  si_[u] += si_[v];
        sr_[v] = dr * w8r - di * w8i;
        si_[v] = dr * w8i + di * w8r;
    }

    // ---- cross-lane stages h=32..2: hi-lane new = (self-other)*wL^(1024/2h) ----
#define SHFL_STAGE(H, PR, PI)                                       \
    {                                                               \
        const int hi_ = lane & (H);                                 \
        _Pragma("unroll")                                           \
        for (int r = 0; r < 16; ++r) {                              \
            float orr = __shfl_xor(sr_[r], (H));                    \
            float oii = __shfl_xor(si_[r], (H));                    \
            float ddr = sr_[r] - orr, ddi = si_[r] - oii;           \
            float ssr = sr_[r] + orr, ssi = si_[r] + oii;           \
            sr_[r] = hi_ ? (ddr * (PR) - ddi * (PI)) : ssr;         \
            si_[r] = hi_ ? (ddr * (PI) + ddi * (PR)) : ssi;         \
        }                                                           \
    }
    SHFL_STAGE(32, w16r,  w16i)
    SHFL_STAGE(16, w32r,  w32i)
    SHFL_STAGE(8,  w64r,  w64i)
    SHFL_STAGE(4,  w128r, w128i)
    SHFL_STAGE(2,  w256r, w256i)
#undef SHFL_STAGE
    // ---- h=1: tw = (-1)^lane -> odd lanes: other - self ----
    {
        const int hi_ = lane & 1;
        #pragma unroll
        for (int r = 0; r < 16; ++r) {
            float orr = __shfl_xor(sr_[r], 1);
            float oii = __shfl_xor(si_[r], 1);
            sr_[r] = hi_ ? (orr - sr_[r]) : (sr_[r] + orr);
            si_[r] = hi_ ? (oii - si_[r]) : (si_[r] + oii);
        }
    }

    // ---- value at (r,lane) is S[f], f = rev6(lane)*16 + rev4(r); f<=512 only
    const int m6 = (int)(__brev((unsigned)lane) >> 26);
    if ((lane & 1) == 0) {
        const int fb = m6 << 4;
        #pragma unroll
        for (int r = 0; r < 16; ++r) {
            const int f = fb + R4_[r];
            ot[OTI(f) + 2 * wv]     = sr_[r];   // ReS = Re A[f]
            ot[OTI(f) + 2 * wv + 1] = si_[r];   // ImS = Re B[f]
        }
    } else if (lane == 1) {
        ot[OTI(512) + 2 * wv]     = sr_[0];     // f = 512 (rev6(1)=32, r=0)
        ot[OTI(512) + 2 * wv + 1] = si_[0];
    }

    __syncthreads();

    // ---- flush: 8 consecutive t per f row (32B segments) ----
    #pragma unroll
    for (int it = 0; it < 17; ++it) {
        const int idx = tid + it * 256;
        if (idx < N_FREQ * FPB) {
            const int f = idx >> 3, c = idx & 7;
            const int t = t0 + c;
            if (t < N_FRAMES) {
                unsigned long long o =
                    (unsigned long long)(b * N_FREQ + f) * N_FRAMES
                    + (unsigned long long)t;
                if (o < cap) out[o] = ot[OTI(f) + c];
            }
        }
    }
}

extern "C" void kernel_launch(void* const* d_in, const int* in_sizes, int n_in,
                              void* d_out, int out_size, void* d_ws, size_t ws_size,
                              hipStream_t stream)
{
    const float* x = (const float*)d_in[0];
    float* out = (float*)d_out;
    if (!x || !out || out_size <= 0) return;

    unsigned long long cap = (unsigned long long)(long long)out_size;

    dim3 grid(BATCH * NTILES);   // 2064 blocks
    dim3 block(256);
    stft_kernel<<<grid, block, 0, stream>>>(x, out, cap);
}